// Round 1
// baseline (976.297 us; speedup 1.0000x reference)
//
#include <hip/hip_runtime.h>

// ---------------------------------------------------------------------------
// ComplexHoloLinear: out[n,r] = sum_k x[n,k] * (Wr[r,k] + cos(phase[b])*Wi[r,k])
// b = n / SEQ.  Wr/Wi are dense-assembled from COO (duplicates sum).
//
// Strategy: scatter -> fold phase into per-batch bf16 weights -> one bf16 MFMA
// GEMM (halves the FLOPs vs the reference's two-GEMM form).
// ---------------------------------------------------------------------------

#define K_IN   4096
#define F_OUT  4096
#define SEQ    2048
#define NROW   8192            // BATCH * SEQ
#define NNZ    4194304
#define WELEM  16777216        // F_OUT * K_IN

typedef float  f32x4  __attribute__((ext_vector_type(4)));
typedef __bf16 bf16x8 __attribute__((ext_vector_type(8)));
typedef unsigned short u16x8 __attribute__((ext_vector_type(8)));

__device__ __forceinline__ unsigned short f2bf(float f) {
  unsigned u = __builtin_bit_cast(unsigned, f);
  u += 0x7fffu + ((u >> 16) & 1u);          // round-to-nearest-even
  return (unsigned short)(u >> 16);
}

// ---------------- 1. scatter COO into dense f32 Wr / Wi -------------------
__global__ __launch_bounds__(256) void scatter_kernel(
    const int* __restrict__ rows, const int* __restrict__ cols,
    const float* __restrict__ wre, const float* __restrict__ wim,
    float* __restrict__ Wr, float* __restrict__ Wi) {
  int e = blockIdx.x * 256 + threadIdx.x;     // grid = NNZ/256 exactly
  int r = rows[e];
  int c = cols[e];
  size_t idx = ((size_t)r << 12) + (size_t)c; // r*4096 + c
  atomicAdd(Wr + idx, wre[e]);
  atomicAdd(Wi + idx, wim[e]);
}

// ---------------- 2. fold phase: Wb[b] = bf16(Wr + cos_b * Wi) ------------
__global__ __launch_bounds__(256) void fold_kernel(
    const float* __restrict__ Wr, const float* __restrict__ Wi,
    const float* __restrict__ phase, unsigned short* __restrict__ Wb) {
  size_t i8 = ((size_t)blockIdx.x * 256 + threadIdx.x) << 3;  // 8 elems/thread
  float cb[4];
  cb[0] = cosf(phase[0]); cb[1] = cosf(phase[1]);
  cb[2] = cosf(phase[2]); cb[3] = cosf(phase[3]);
  f32x4 r0 = *(const f32x4*)(Wr + i8);
  f32x4 r1 = *(const f32x4*)(Wr + i8 + 4);
  f32x4 i0 = *(const f32x4*)(Wi + i8);
  f32x4 i1 = *(const f32x4*)(Wi + i8 + 4);
  #pragma unroll
  for (int b = 0; b < 4; ++b) {
    float c = cb[b];
    u16x8 v;
    v[0] = f2bf(r0[0] + c * i0[0]); v[1] = f2bf(r0[1] + c * i0[1]);
    v[2] = f2bf(r0[2] + c * i0[2]); v[3] = f2bf(r0[3] + c * i0[3]);
    v[4] = f2bf(r1[0] + c * i1[0]); v[5] = f2bf(r1[1] + c * i1[1]);
    v[6] = f2bf(r1[2] + c * i1[2]); v[7] = f2bf(r1[3] + c * i1[3]);
    *(u16x8*)(Wb + ((size_t)b << 24) + i8) = v;   // b * 16777216 elems
  }
}

// ---------------- 3. x f32 -> bf16 ----------------------------------------
__global__ __launch_bounds__(256) void xconv_kernel(
    const float* __restrict__ x, unsigned short* __restrict__ Xb) {
  size_t i8 = ((size_t)blockIdx.x * 256 + threadIdx.x) << 3;
  f32x4 a = *(const f32x4*)(x + i8);
  f32x4 b = *(const f32x4*)(x + i8 + 4);
  u16x8 v;
  v[0] = f2bf(a[0]); v[1] = f2bf(a[1]); v[2] = f2bf(a[2]); v[3] = f2bf(a[3]);
  v[4] = f2bf(b[0]); v[5] = f2bf(b[1]); v[6] = f2bf(b[2]); v[7] = f2bf(b[3]);
  *(u16x8*)(Xb + i8) = v;
}

// ---------------- 4. bf16 GEMM: out = Xb @ Wb[batch]^T --------------------
// 128x128 tile, BK=64, 256 thr (4 waves 2x2), 4x4 mfma_f32_16x16x32_bf16/wave,
// global_load_lds width-16 staging (m97 structure).
#define GLOAD_LDS(g, l)                                                        \
  __builtin_amdgcn_global_load_lds(                                            \
      (const __attribute__((address_space(1))) unsigned int*)(g),              \
      (__attribute__((address_space(3))) unsigned int*)(l), 16, 0, 0)

__global__ __launch_bounds__(256) void gemm_kernel(
    const unsigned short* __restrict__ Xb,   // [8192][4096] bf16 bits
    const unsigned short* __restrict__ Wb,   // [4][4096][4096] bf16 bits
    float* __restrict__ out) {               // [8192][4096] f32
  __shared__ unsigned short ldsA[128 * 64];
  __shared__ unsigned short ldsB[128 * 64];

  const int tid  = threadIdx.x;
  const int wid  = tid >> 6;
  const int lane = tid & 63;
  const int brow = blockIdx.x >> 5;          // 64 row-blocks
  const int bcol = blockIdx.x & 31;          // 32 col-blocks
  const int wrw  = wid >> 1;                 // wave row 0..1
  const int wcw  = wid & 1;                  // wave col 0..1

  const size_t M0 = (size_t)brow << 7;       // *128
  const int batch = (int)(M0 >> 11);         // /2048
  const unsigned short* Ap = Xb + M0 * K_IN;
  const unsigned short* Bp = Wb + ((size_t)batch << 24) + (((size_t)bcol << 7) * K_IN);

  const int srow = lane >> 3;                // 0..7  (row within 8-row chunk)
  const int scol = (lane & 7) << 3;          // 0..56 (k element offset, 16B)
  const int lrow = lane & 15;
  const int lkb  = (lane >> 4) << 3;         // k sub-offset 0/8/16/24

  f32x4 acc[4][4] = {};

  for (int k0 = 0; k0 < K_IN; k0 += 64) {
    #pragma unroll
    for (int c = 0; c < 4; ++c) {
      const int rb = ((wid << 2) + c) << 3;  // 8-row chunk base, per-wave
      const size_t go = (size_t)(rb + srow) * K_IN + (size_t)(k0 + scol);
      GLOAD_LDS(Ap + go, &ldsA[rb << 6]);
      GLOAD_LDS(Bp + go, &ldsB[rb << 6]);
    }
    __syncthreads();   // compiler drains vmcnt before s_barrier

    #pragma unroll
    for (int kk = 0; kk < 64; kk += 32) {
      bf16x8 af[4], bf[4];
      #pragma unroll
      for (int mi = 0; mi < 4; ++mi)
        af[mi] = *(const bf16x8*)&ldsA[(((wrw << 6) + (mi << 4) + lrow) << 6) + kk + lkb];
      #pragma unroll
      for (int ni = 0; ni < 4; ++ni)
        bf[ni] = *(const bf16x8*)&ldsB[(((wcw << 6) + (ni << 4) + lrow) << 6) + kk + lkb];
      #pragma unroll
      for (int mi = 0; mi < 4; ++mi)
        #pragma unroll
        for (int ni = 0; ni < 4; ++ni)
          acc[mi][ni] = __builtin_amdgcn_mfma_f32_16x16x32_bf16(
              af[mi], bf[ni], acc[mi][ni], 0, 0, 0);
    }
    __syncthreads();
  }

  // epilogue: C/D layout col = lane&15, row = (lane>>4)*4 + j  [m89/m91]
  const int ch = lane >> 4;
  float* op = out + (M0 + (size_t)(wrw << 6)) * F_OUT + ((size_t)bcol << 7) + (wcw << 6);
  #pragma unroll
  for (int mi = 0; mi < 4; ++mi)
    #pragma unroll
    for (int ni = 0; ni < 4; ++ni)
      #pragma unroll
      for (int j = 0; j < 4; ++j)
        op[(size_t)((mi << 4) + (ch << 2) + j) * F_OUT + (ni << 4) + lrow] = acc[mi][ni][j];
}

// ---------------- fallback (small ws): naive f32 ---------------------------
__global__ __launch_bounds__(256) void naive_kernel(
    const float* __restrict__ x, const float* __restrict__ Wr,
    const float* __restrict__ Wi, const float* __restrict__ phase,
    float* __restrict__ out) {
  int n = blockIdx.x >> 4;
  int r = ((blockIdx.x & 15) << 8) | threadIdx.x;
  float cb = cosf(phase[n >> 11]);
  const float* xp = x + ((size_t)n << 12);
  const float* wr = Wr + ((size_t)r << 12);
  const float* wi = Wi + ((size_t)r << 12);
  float ar = 0.f, ai = 0.f;
  for (int k = 0; k < K_IN; ++k) {
    float xv = xp[k];
    ar += xv * wr[k];
    ai += xv * wi[k];
  }
  out[((size_t)n << 12) + r] = ar + cb * ai;
}

// ---------------------------------------------------------------------------
extern "C" void kernel_launch(void* const* d_in, const int* in_sizes, int n_in,
                              void* d_out, int out_size, void* d_ws, size_t ws_size,
                              hipStream_t stream) {
  const float* x     = (const float*)d_in[0];
  const int*   rows  = (const int*)d_in[1];
  const int*   cols  = (const int*)d_in[2];
  const float* wre   = (const float*)d_in[3];
  const float* wim   = (const float*)d_in[4];
  const float* phase = (const float*)d_in[5];
  float* out = (float*)d_out;

  float* Wr = (float*)d_ws;                  // [0, 64MB)   f32
  float* Wi = Wr + WELEM;                    // [64, 128MB) f32

  hipMemsetAsync(d_ws, 0, (size_t)2 * WELEM * sizeof(float), stream);
  scatter_kernel<<<NNZ / 256, 256, 0, stream>>>(rows, cols, wre, wim, Wr, Wi);

  const size_t WS_MAIN = (size_t)268435456;  // 256MB
  if (ws_size >= WS_MAIN) {
    unsigned short* Wb = (unsigned short*)((char*)d_ws + (size_t)134217728); // [128,256MB) bf16 x4 batches
    unsigned short* Xb = (unsigned short*)d_ws;  // reuses dead Wr f32 region [0,64MB)
    fold_kernel<<<WELEM / 8 / 256, 256, 0, stream>>>(Wr, Wi, phase, Wb);
    xconv_kernel<<<(size_t)NROW * K_IN / 8 / 256, 256, 0, stream>>>(x, Xb);
    gemm_kernel<<<2048, 256, 0, stream>>>(Xb, Wb, out);
  } else {
    naive_kernel<<<NROW * 16, 256, 0, stream>>>(x, Wr, Wi, phase, out);
  }
}

// Round 2
// 897.797 us; speedup vs baseline: 1.0874x; 1.0874x over previous
//
#include <hip/hip_runtime.h>

// ---------------------------------------------------------------------------
// ComplexHoloLinear: out[n,r] = sum_k x[n,k] * (Wr[r,k] + cos(phase[b])*Wi[r,k])
// b = n / SEQ.  Wr/Wi dense-assembled from COO (duplicates sum).
//
// Pipeline: memset -> scatter (float2-interleaved atomics) -> fold phase into
// per-batch bf16 weights -> x->bf16 -> one bf16 MFMA GEMM (XOR-swizzled LDS).
// ---------------------------------------------------------------------------

#define K_IN   4096
#define F_OUT  4096
#define SEQ    2048
#define NROW   8192            // BATCH * SEQ
#define NNZ    4194304
#define WELEM  16777216        // F_OUT * K_IN

typedef float  f32x4  __attribute__((ext_vector_type(4)));
typedef __bf16 bf16x8 __attribute__((ext_vector_type(8)));
typedef unsigned short u16x8 __attribute__((ext_vector_type(8)));

__device__ __forceinline__ unsigned short f2bf(float f) {
  unsigned u = __builtin_bit_cast(unsigned, f);
  u += 0x7fffu + ((u >> 16) & 1u);          // round-to-nearest-even
  return (unsigned short)(u >> 16);
}

// ---------------- 1. scatter COO into interleaved f32x2 Wc ----------------
// Wc[idx] = (sum w_real, sum w_imag) -- both atomics hit one cacheline.
__global__ __launch_bounds__(256) void scatter_kernel(
    const int* __restrict__ rows, const int* __restrict__ cols,
    const float* __restrict__ wre, const float* __restrict__ wim,
    float* __restrict__ Wc) {
  int e = blockIdx.x * 256 + threadIdx.x;     // grid = NNZ/256 exactly
  int r = rows[e];
  int c = cols[e];
  size_t idx2 = (((size_t)r << 12) + (size_t)c) << 1; // (r*4096+c)*2
  atomicAdd(Wc + idx2,     wre[e]);
  atomicAdd(Wc + idx2 + 1, wim[e]);
}

// ---------------- 2. fold phase: Wb[b] = bf16(Wr + cos_b * Wi) ------------
__global__ __launch_bounds__(256) void fold_kernel(
    const float* __restrict__ Wc, const float* __restrict__ phase,
    unsigned short* __restrict__ Wb) {
  size_t i8 = ((size_t)blockIdx.x * 256 + threadIdx.x) << 3;  // 8 logical elems
  float cb[4];
  cb[0] = cosf(phase[0]); cb[1] = cosf(phase[1]);
  cb[2] = cosf(phase[2]); cb[3] = cosf(phase[3]);
  const float* p = Wc + (i8 << 1);
  f32x4 q0 = *(const f32x4*)(p);      // r0 i0 r1 i1
  f32x4 q1 = *(const f32x4*)(p + 4);  // r2 i2 r3 i3
  f32x4 q2 = *(const f32x4*)(p + 8);  // r4 i4 r5 i5
  f32x4 q3 = *(const f32x4*)(p + 12); // r6 i6 r7 i7
  #pragma unroll
  for (int b = 0; b < 4; ++b) {
    float c = cb[b];
    u16x8 v;
    v[0] = f2bf(q0[0] + c * q0[1]); v[1] = f2bf(q0[2] + c * q0[3]);
    v[2] = f2bf(q1[0] + c * q1[1]); v[3] = f2bf(q1[2] + c * q1[3]);
    v[4] = f2bf(q2[0] + c * q2[1]); v[5] = f2bf(q2[2] + c * q2[3]);
    v[6] = f2bf(q3[0] + c * q3[1]); v[7] = f2bf(q3[2] + c * q3[3]);
    *(u16x8*)(Wb + ((size_t)b << 24) + i8) = v;   // b * 16777216 elems
  }
}

// ---------------- 3. x f32 -> bf16 ----------------------------------------
__global__ __launch_bounds__(256) void xconv_kernel(
    const float* __restrict__ x, unsigned short* __restrict__ Xb) {
  size_t i8 = ((size_t)blockIdx.x * 256 + threadIdx.x) << 3;
  f32x4 a = *(const f32x4*)(x + i8);
  f32x4 b = *(const f32x4*)(x + i8 + 4);
  u16x8 v;
  v[0] = f2bf(a[0]); v[1] = f2bf(a[1]); v[2] = f2bf(a[2]); v[3] = f2bf(a[3]);
  v[4] = f2bf(b[0]); v[5] = f2bf(b[1]); v[6] = f2bf(b[2]); v[7] = f2bf(b[3]);
  *(u16x8*)(Xb + i8) = v;
}

// ---------------- 4. bf16 GEMM: out = Xb @ Wb[batch]^T --------------------
// 128x128 tile, BK=64, 256 thr (4 waves 2x2), 4x4 mfma_f32_16x16x32_bf16/wave.
// T2 XOR-swizzle: LDS stays linear-dest for global_load_lds; the per-lane
// GLOBAL source is pre-swizzled (slot ^= row&7) and ds_read applies the same
// XOR (involution) -> conflict-free reads (rule #21 both-sides pattern).
#define GLOAD_LDS(g, l)                                                        \
  __builtin_amdgcn_global_load_lds(                                            \
      (const __attribute__((address_space(1))) unsigned int*)(g),              \
      (__attribute__((address_space(3))) unsigned int*)(l), 16, 0, 0)

__global__ __launch_bounds__(256) void gemm_kernel(
    const unsigned short* __restrict__ Xb,   // [8192][4096] bf16 bits
    const unsigned short* __restrict__ Wb,   // [4][4096][4096] bf16 bits
    float* __restrict__ out) {               // [8192][4096] f32
  __shared__ unsigned short ldsA[128 * 64];
  __shared__ unsigned short ldsB[128 * 64];

  const int tid  = threadIdx.x;
  const int wid  = tid >> 6;
  const int lane = tid & 63;
  const int brow = blockIdx.x >> 5;          // 64 row-blocks
  const int bcol = blockIdx.x & 31;          // 32 col-blocks
  const int wrw  = wid >> 1;                 // wave row 0..1
  const int wcw  = wid & 1;                  // wave col 0..1

  const size_t M0 = (size_t)brow << 7;       // *128
  const int batch = (int)(M0 >> 11);         // /2048
  const unsigned short* Ap = Xb + M0 * K_IN;
  const unsigned short* Bp = Wb + ((size_t)batch << 24) + (((size_t)bcol << 7) * K_IN);

  // staging geometry: row = chunk_base + srow, slot = lane&7 (16B units)
  const int srow = lane >> 3;                // 0..7  == row&7 (chunks are 8-aligned)
  const int gslot = ((lane & 7) ^ srow) << 3; // pre-swizzled k-elem offset
  // fragment-read geometry
  const int lrow = lane & 15;
  const int lr7  = lrow & 7;
  const int sb   = lane >> 4;                // 0..3 (k sub-slot base)
  const int swzc[2] = { ((sb ^ lr7) << 3), (((sb + 4) ^ lr7) << 3) };

  f32x4 acc[4][4] = {};

  for (int k0 = 0; k0 < K_IN; k0 += 64) {
    #pragma unroll
    for (int c = 0; c < 4; ++c) {
      const int rb = ((wid << 2) + c) << 3;  // 8-row chunk base, per-wave
      const size_t go = (size_t)(rb + srow) * K_IN + (size_t)(k0 + gslot);
      GLOAD_LDS(Ap + go, &ldsA[rb << 6]);
      GLOAD_LDS(Bp + go, &ldsB[rb << 6]);
    }
    __syncthreads();   // compiler drains vmcnt before s_barrier

    #pragma unroll
    for (int t = 0; t < 2; ++t) {            // kk = t*32
      const int col = swzc[t];
      bf16x8 af[4], bff[4];
      #pragma unroll
      for (int mi = 0; mi < 4; ++mi)
        af[mi] = *(const bf16x8*)&ldsA[(((wrw << 6) + (mi << 4) + lrow) << 6) + col];
      #pragma unroll
      for (int ni = 0; ni < 4; ++ni)
        bff[ni] = *(const bf16x8*)&ldsB[(((wcw << 6) + (ni << 4) + lrow) << 6) + col];
      #pragma unroll
      for (int mi = 0; mi < 4; ++mi)
        #pragma unroll
        for (int ni = 0; ni < 4; ++ni)
          acc[mi][ni] = __builtin_amdgcn_mfma_f32_16x16x32_bf16(
              af[mi], bff[ni], acc[mi][ni], 0, 0, 0);
    }
    __syncthreads();
  }

  // epilogue: C/D layout col = lane&15, row = (lane>>4)*4 + j  [m89/m91]
  const int ch = lane >> 4;
  float* op = out + (M0 + (size_t)(wrw << 6)) * F_OUT + ((size_t)bcol << 7) + (wcw << 6);
  #pragma unroll
  for (int mi = 0; mi < 4; ++mi)
    #pragma unroll
    for (int ni = 0; ni < 4; ++ni)
      #pragma unroll
      for (int j = 0; j < 4; ++j)
        op[(size_t)((mi << 4) + (ch << 2) + j) * F_OUT + (ni << 4) + lrow] = acc[mi][ni][j];
}

// ---------------- fallback (small ws): naive f32 ---------------------------
__global__ __launch_bounds__(256) void naive_kernel(
    const float* __restrict__ x, const float* __restrict__ Wc,
    const float* __restrict__ phase, float* __restrict__ out) {
  int n = blockIdx.x >> 4;
  int r = ((blockIdx.x & 15) << 8) | threadIdx.x;
  float cb = cosf(phase[n >> 11]);
  const float* xp = x + ((size_t)n << 12);
  const float* wc = Wc + (((size_t)r << 12) << 1);
  float ar = 0.f, ai = 0.f;
  for (int k = 0; k < K_IN; ++k) {
    float xv = xp[k];
    ar += xv * wc[2 * k];
    ai += xv * wc[2 * k + 1];
  }
  out[((size_t)n << 12) + r] = ar + cb * ai;
}

// ---------------------------------------------------------------------------
extern "C" void kernel_launch(void* const* d_in, const int* in_sizes, int n_in,
                              void* d_out, int out_size, void* d_ws, size_t ws_size,
                              hipStream_t stream) {
  const float* x     = (const float*)d_in[0];
  const int*   rows  = (const int*)d_in[1];
  const int*   cols  = (const int*)d_in[2];
  const float* wre   = (const float*)d_in[3];
  const float* wim   = (const float*)d_in[4];
  const float* phase = (const float*)d_in[5];
  float* out = (float*)d_out;

  float* Wc = (float*)d_ws;                  // [0, 128MB) interleaved f32x2

  hipMemsetAsync(d_ws, 0, (size_t)2 * WELEM * sizeof(float), stream);
  scatter_kernel<<<NNZ / 256, 256, 0, stream>>>(rows, cols, wre, wim, Wc);

  const size_t WS_MAIN = (size_t)268435456;  // 256MB
  if (ws_size >= WS_MAIN) {
    unsigned short* Wb = (unsigned short*)((char*)d_ws + (size_t)134217728); // [128,256MB) bf16 x4
    unsigned short* Xb = (unsigned short*)d_ws;  // reuses Wc region after fold (stream-ordered)
    fold_kernel<<<WELEM / 8 / 256, 256, 0, stream>>>(Wc, phase, Wb);
    xconv_kernel<<<(size_t)NROW * K_IN / 8 / 256, 256, 0, stream>>>(x, Xb);
    gemm_kernel<<<2048, 256, 0, stream>>>(Xb, Wb, out);
  } else {
    naive_kernel<<<NROW * 16, 256, 0, stream>>>(x, Wc, phase, out);
  }
}

// Round 3
// 668.279 us; speedup vs baseline: 1.4609x; 1.3434x over previous
//
#include <hip/hip_runtime.h>

// ---------------------------------------------------------------------------
// ComplexHoloLinear: out[n,r] = sum_k x[n,k] * (Wr[r,k] + cos(phase[b])*Wi[r,k])
// b = n / SEQ.  Wr/Wi dense-assembled from COO (duplicates sum).
//
// Pipeline: memset -> scatter (ONE global_atomic_pk_add_bf16 per entry into
// interleaved bf16 (r,i) table) -> fold phase into per-batch bf16 weights ->
// x->bf16 -> one bf16 MFMA GEMM (XOR-swizzled LDS, m97 structure).
// ---------------------------------------------------------------------------

#define K_IN   4096
#define F_OUT  4096
#define SEQ    2048
#define NROW   8192            // BATCH * SEQ
#define NNZ    4194304
#define WELEM  16777216        // F_OUT * K_IN

typedef float  f32x4  __attribute__((ext_vector_type(4)));
typedef __bf16 bf16x8 __attribute__((ext_vector_type(8)));
typedef unsigned short u16x8 __attribute__((ext_vector_type(8)));

__device__ __forceinline__ unsigned short f2bf(float f) {
  unsigned u = __builtin_bit_cast(unsigned, f);
  u += 0x7fffu + ((u >> 16) & 1u);          // round-to-nearest-even
  return (unsigned short)(u >> 16);
}
__device__ __forceinline__ float bf2f(unsigned short b) {
  return __builtin_bit_cast(float, (unsigned)b << 16);
}

// ---------------- 1. scatter COO: one pk_add_bf16 per entry ---------------
// Wcb[idx] = (sum w_real, sum w_imag) as interleaved bf16 pair (4B/slot).
__global__ __launch_bounds__(256) void scatter_kernel(
    const int* __restrict__ rows, const int* __restrict__ cols,
    const float* __restrict__ wre, const float* __restrict__ wim,
    unsigned short* __restrict__ Wcb) {
  int e = blockIdx.x * 256 + threadIdx.x;     // grid = NNZ/256 exactly
  int r = rows[e];
  int c = cols[e];
  unsigned pk = (unsigned)f2bf(wre[e]) | ((unsigned)f2bf(wim[e]) << 16);
  size_t idx = ((size_t)r << 12) + (size_t)c; // r*4096 + c
  // low 16b -> Wcb[2*idx] (real), high 16b -> Wcb[2*idx+1] (imag)
  asm volatile("global_atomic_pk_add_bf16 %0, %1, off"
               :: "v"(Wcb + (idx << 1)), "v"(pk) : "memory");
}

// ---------------- 2. fold phase: Wb[b] = bf16(Wr + cos_b * Wi) ------------
__global__ __launch_bounds__(256) void fold_kernel(
    const unsigned short* __restrict__ Wcb, const float* __restrict__ phase,
    unsigned short* __restrict__ Wb) {
  size_t i8 = ((size_t)blockIdx.x * 256 + threadIdx.x) << 3;  // 8 logical elems
  float cb[4];
  cb[0] = cosf(phase[0]); cb[1] = cosf(phase[1]);
  cb[2] = cosf(phase[2]); cb[3] = cosf(phase[3]);
  const unsigned short* p = Wcb + (i8 << 1);   // 16 shorts = 8 (r,i) pairs
  u16x8 a = *(const u16x8*)(p);
  u16x8 b = *(const u16x8*)(p + 8);
  float rr[8], ii[8];
  rr[0] = bf2f(a[0]); ii[0] = bf2f(a[1]);
  rr[1] = bf2f(a[2]); ii[1] = bf2f(a[3]);
  rr[2] = bf2f(a[4]); ii[2] = bf2f(a[5]);
  rr[3] = bf2f(a[6]); ii[3] = bf2f(a[7]);
  rr[4] = bf2f(b[0]); ii[4] = bf2f(b[1]);
  rr[5] = bf2f(b[2]); ii[5] = bf2f(b[3]);
  rr[6] = bf2f(b[4]); ii[6] = bf2f(b[5]);
  rr[7] = bf2f(b[6]); ii[7] = bf2f(b[7]);
  #pragma unroll
  for (int bb = 0; bb < 4; ++bb) {
    float c = cb[bb];
    u16x8 v;
    #pragma unroll
    for (int j = 0; j < 8; ++j) v[j] = f2bf(rr[j] + c * ii[j]);
    *(u16x8*)(Wb + ((size_t)bb << 24) + i8) = v;   // bb * 16777216 elems
  }
}

// ---------------- 3. x f32 -> bf16 ----------------------------------------
__global__ __launch_bounds__(256) void xconv_kernel(
    const float* __restrict__ x, unsigned short* __restrict__ Xb) {
  size_t i8 = ((size_t)blockIdx.x * 256 + threadIdx.x) << 3;
  f32x4 a = *(const f32x4*)(x + i8);
  f32x4 b = *(const f32x4*)(x + i8 + 4);
  u16x8 v;
  v[0] = f2bf(a[0]); v[1] = f2bf(a[1]); v[2] = f2bf(a[2]); v[3] = f2bf(a[3]);
  v[4] = f2bf(b[0]); v[5] = f2bf(b[1]); v[6] = f2bf(b[2]); v[7] = f2bf(b[3]);
  *(u16x8*)(Xb + i8) = v;
}

// ---------------- 4. bf16 GEMM: out = Xb @ Wb[batch]^T --------------------
// 128x128 tile, BK=64, 256 thr (4 waves 2x2), 4x4 mfma_f32_16x16x32_bf16/wave.
// T2 XOR-swizzle: LDS linear-dest for global_load_lds; per-lane GLOBAL source
// pre-swizzled (slot ^= row&7); ds_read applies the same XOR (involution).
#define GLOAD_LDS(g, l)                                                        \
  __builtin_amdgcn_global_load_lds(                                            \
      (const __attribute__((address_space(1))) unsigned int*)(g),              \
      (__attribute__((address_space(3))) unsigned int*)(l), 16, 0, 0)

__global__ __launch_bounds__(256) void gemm_kernel(
    const unsigned short* __restrict__ Xb,   // [8192][4096] bf16 bits
    const unsigned short* __restrict__ Wb,   // [4][4096][4096] bf16 bits
    float* __restrict__ out) {               // [8192][4096] f32
  __shared__ unsigned short ldsA[128 * 64];
  __shared__ unsigned short ldsB[128 * 64];

  const int tid  = threadIdx.x;
  const int wid  = tid >> 6;
  const int lane = tid & 63;
  const int brow = blockIdx.x >> 5;          // 64 row-blocks
  const int bcol = blockIdx.x & 31;          // 32 col-blocks
  const int wrw  = wid >> 1;                 // wave row 0..1
  const int wcw  = wid & 1;                  // wave col 0..1

  const size_t M0 = (size_t)brow << 7;       // *128
  const int batch = (int)(M0 >> 11);         // /2048
  const unsigned short* Ap = Xb + M0 * K_IN;
  const unsigned short* Bp = Wb + ((size_t)batch << 24) + (((size_t)bcol << 7) * K_IN);

  // staging geometry: row = chunk_base + srow, slot = lane&7 (16B units)
  const int srow = lane >> 3;                // 0..7  == row&7 (chunks are 8-aligned)
  const int gslot = ((lane & 7) ^ srow) << 3; // pre-swizzled k-elem offset
  // fragment-read geometry
  const int lrow = lane & 15;
  const int lr7  = lrow & 7;
  const int sb   = lane >> 4;                // 0..3 (k sub-slot base)
  const int swzc[2] = { ((sb ^ lr7) << 3), (((sb + 4) ^ lr7) << 3) };

  f32x4 acc[4][4] = {};

  for (int k0 = 0; k0 < K_IN; k0 += 64) {
    #pragma unroll
    for (int c = 0; c < 4; ++c) {
      const int rb = ((wid << 2) + c) << 3;  // 8-row chunk base, per-wave
      const size_t go = (size_t)(rb + srow) * K_IN + (size_t)(k0 + gslot);
      GLOAD_LDS(Ap + go, &ldsA[rb << 6]);
      GLOAD_LDS(Bp + go, &ldsB[rb << 6]);
    }
    __syncthreads();   // compiler drains vmcnt before s_barrier

    #pragma unroll
    for (int t = 0; t < 2; ++t) {            // kk = t*32
      const int col = swzc[t];
      bf16x8 af[4], bff[4];
      #pragma unroll
      for (int mi = 0; mi < 4; ++mi)
        af[mi] = *(const bf16x8*)&ldsA[(((wrw << 6) + (mi << 4) + lrow) << 6) + col];
      #pragma unroll
      for (int ni = 0; ni < 4; ++ni)
        bff[ni] = *(const bf16x8*)&ldsB[(((wcw << 6) + (ni << 4) + lrow) << 6) + col];
      #pragma unroll
      for (int mi = 0; mi < 4; ++mi)
        #pragma unroll
        for (int ni = 0; ni < 4; ++ni)
          acc[mi][ni] = __builtin_amdgcn_mfma_f32_16x16x32_bf16(
              af[mi], bff[ni], acc[mi][ni], 0, 0, 0);
    }
    __syncthreads();
  }

  // epilogue: C/D layout col = lane&15, row = (lane>>4)*4 + j  [m89/m91]
  const int ch = lane >> 4;
  float* op = out + (M0 + (size_t)(wrw << 6)) * F_OUT + ((size_t)bcol << 7) + (wcw << 6);
  #pragma unroll
  for (int mi = 0; mi < 4; ++mi)
    #pragma unroll
    for (int ni = 0; ni < 4; ++ni)
      #pragma unroll
      for (int j = 0; j < 4; ++j)
        op[(size_t)((mi << 4) + (ch << 2) + j) * F_OUT + (ni << 4) + lrow] = acc[mi][ni][j];
}

// ---------------- fallback (small ws): naive, reads bf16 pairs -------------
__global__ __launch_bounds__(256) void naive_kernel(
    const float* __restrict__ x, const unsigned short* __restrict__ Wcb,
    const float* __restrict__ phase, float* __restrict__ out) {
  int n = blockIdx.x >> 4;
  int r = ((blockIdx.x & 15) << 8) | threadIdx.x;
  float cb = cosf(phase[n >> 11]);
  const float* xp = x + ((size_t)n << 12);
  const unsigned short* wc = Wcb + (((size_t)r << 12) << 1);
  float ar = 0.f, ai = 0.f;
  for (int k = 0; k < K_IN; ++k) {
    float xv = xp[k];
    ar += xv * bf2f(wc[2 * k]);
    ai += xv * bf2f(wc[2 * k + 1]);
  }
  out[((size_t)n << 12) + r] = ar + cb * ai;
}

// ---------------------------------------------------------------------------
extern "C" void kernel_launch(void* const* d_in, const int* in_sizes, int n_in,
                              void* d_out, int out_size, void* d_ws, size_t ws_size,
                              hipStream_t stream) {
  const float* x     = (const float*)d_in[0];
  const int*   rows  = (const int*)d_in[1];
  const int*   cols  = (const int*)d_in[2];
  const float* wre   = (const float*)d_in[3];
  const float* wim   = (const float*)d_in[4];
  const float* phase = (const float*)d_in[5];
  float* out = (float*)d_out;

  unsigned short* Wcb = (unsigned short*)d_ws;   // [0, 64MB) bf16 (r,i) pairs

  hipMemsetAsync(d_ws, 0, (size_t)WELEM * 4, stream);   // 64MB
  scatter_kernel<<<NNZ / 256, 256, 0, stream>>>(rows, cols, wre, wim, Wcb);

  const size_t WS_MAIN = (size_t)201326592;  // 192MB
  if (ws_size >= WS_MAIN) {
    unsigned short* Wb = (unsigned short*)((char*)d_ws + (size_t)67108864); // [64,192MB) bf16 x4
    unsigned short* Xb = (unsigned short*)d_ws;  // reuses Wcb region after fold (stream-ordered)
    fold_kernel<<<WELEM / 8 / 256, 256, 0, stream>>>(Wcb, phase, Wb);
    xconv_kernel<<<(size_t)NROW * K_IN / 8 / 256, 256, 0, stream>>>(x, Xb);
    gemm_kernel<<<2048, 256, 0, stream>>>(Xb, Wb, out);
  } else {
    naive_kernel<<<NROW * 16, 256, 0, stream>>>(x, Wcb, phase, out);
  }
}

// Round 4
// 520.353 us; speedup vs baseline: 1.8762x; 1.2843x over previous
//
#include <hip/hip_runtime.h>

// ---------------------------------------------------------------------------
// ComplexHoloLinear: out[n,r] = sum_k x[n,k] * (Wr[r,k] + cos(phase[b])*Wi[r,k])
// b = n / SEQ.  Wr/Wi dense-assembled from COO (duplicates sum).
//
// Pipeline: memset -> scatter (one global_atomic_pk_add_bf16 per entry) ->
// fold phase into per-batch bf16 weights -> x->bf16 -> bf16 MFMA GEMM
// (256x256 tile, counted-vmcnt double-buffer pipeline, XOR-swizzled LDS).
// ---------------------------------------------------------------------------

#define K_IN   4096
#define F_OUT  4096
#define SEQ    2048
#define NROW   8192            // BATCH * SEQ
#define NNZ    4194304
#define WELEM  16777216        // F_OUT * K_IN

typedef float  f32x4  __attribute__((ext_vector_type(4)));
typedef __bf16 bf16x8 __attribute__((ext_vector_type(8)));
typedef unsigned short u16x8 __attribute__((ext_vector_type(8)));

__device__ __forceinline__ unsigned short f2bf(float f) {
  unsigned u = __builtin_bit_cast(unsigned, f);
  u += 0x7fffu + ((u >> 16) & 1u);          // round-to-nearest-even
  return (unsigned short)(u >> 16);
}
__device__ __forceinline__ float bf2f(unsigned short b) {
  return __builtin_bit_cast(float, (unsigned)b << 16);
}

// ---------------- 1. scatter COO: one pk_add_bf16 per entry ---------------
__global__ __launch_bounds__(256) void scatter_kernel(
    const int* __restrict__ rows, const int* __restrict__ cols,
    const float* __restrict__ wre, const float* __restrict__ wim,
    unsigned short* __restrict__ Wcb) {
  int e = blockIdx.x * 256 + threadIdx.x;     // grid = NNZ/256 exactly
  int r = rows[e];
  int c = cols[e];
  unsigned pk = (unsigned)f2bf(wre[e]) | ((unsigned)f2bf(wim[e]) << 16);
  size_t idx = ((size_t)r << 12) + (size_t)c; // r*4096 + c
  asm volatile("global_atomic_pk_add_bf16 %0, %1, off"
               :: "v"(Wcb + (idx << 1)), "v"(pk) : "memory");
}

// ---------------- 2. fold phase: Wb[b] = bf16(Wr + cos_b * Wi) ------------
__global__ __launch_bounds__(256) void fold_kernel(
    const unsigned short* __restrict__ Wcb, const float* __restrict__ phase,
    unsigned short* __restrict__ Wb) {
  size_t i8 = ((size_t)blockIdx.x * 256 + threadIdx.x) << 3;  // 8 logical elems
  float cb[4];
  cb[0] = cosf(phase[0]); cb[1] = cosf(phase[1]);
  cb[2] = cosf(phase[2]); cb[3] = cosf(phase[3]);
  const unsigned short* p = Wcb + (i8 << 1);   // 16 shorts = 8 (r,i) pairs
  u16x8 a = *(const u16x8*)(p);
  u16x8 b = *(const u16x8*)(p + 8);
  float rr[8], ii[8];
  rr[0] = bf2f(a[0]); ii[0] = bf2f(a[1]);
  rr[1] = bf2f(a[2]); ii[1] = bf2f(a[3]);
  rr[2] = bf2f(a[4]); ii[2] = bf2f(a[5]);
  rr[3] = bf2f(a[6]); ii[3] = bf2f(a[7]);
  rr[4] = bf2f(b[0]); ii[4] = bf2f(b[1]);
  rr[5] = bf2f(b[2]); ii[5] = bf2f(b[3]);
  rr[6] = bf2f(b[4]); ii[6] = bf2f(b[5]);
  rr[7] = bf2f(b[6]); ii[7] = bf2f(b[7]);
  #pragma unroll
  for (int bb = 0; bb < 4; ++bb) {
    float c = cb[bb];
    u16x8 v;
    #pragma unroll
    for (int j = 0; j < 8; ++j) v[j] = f2bf(rr[j] + c * ii[j]);
    *(u16x8*)(Wb + ((size_t)bb << 24) + i8) = v;   // bb * 16777216 elems
  }
}

// ---------------- 3. x f32 -> bf16 ----------------------------------------
__global__ __launch_bounds__(256) void xconv_kernel(
    const float* __restrict__ x, unsigned short* __restrict__ Xb) {
  size_t i8 = ((size_t)blockIdx.x * 256 + threadIdx.x) << 3;
  f32x4 a = *(const f32x4*)(x + i8);
  f32x4 b = *(const f32x4*)(x + i8 + 4);
  u16x8 v;
  v[0] = f2bf(a[0]); v[1] = f2bf(a[1]); v[2] = f2bf(a[2]); v[3] = f2bf(a[3]);
  v[4] = f2bf(b[0]); v[5] = f2bf(b[1]); v[6] = f2bf(b[2]); v[7] = f2bf(b[3]);
  *(u16x8*)(Xb + i8) = v;
}

// ---------------- 4. bf16 GEMM: out = Xb @ Wb[batch]^T --------------------
// 256x256 tile, BK=64, 512 thr (8 waves 2x4), per-wave 128x64 output
// (8x4 frags of mfma_f32_16x16x32_bf16). Double-buffered 128KB LDS.
// T4: counted s_waitcnt vmcnt(8) + raw s_barrier keep next tile's
// global_load_lds in flight across the whole compute phase (no drain).
// T2: source-preswizzled slot ^= row&7 (proved 0 conflicts in R2/R3).
// T5: setprio around the 32-MFMA clusters.  T1: bijective XCD swizzle.
#define GLOAD_LDS(g, l)                                                        \
  __builtin_amdgcn_global_load_lds(                                            \
      (const __attribute__((address_space(1))) unsigned int*)(g),              \
      (__attribute__((address_space(3))) unsigned int*)(l), 16, 0, 0)

__global__ __launch_bounds__(512, 2) void gemm_kernel(
    const unsigned short* __restrict__ Xb,   // [8192][4096] bf16 bits
    const unsigned short* __restrict__ Wb,   // [4][4096][4096] bf16 bits
    float* __restrict__ out) {               // [8192][4096] f32
  __shared__ unsigned short lds[65536];      // 128KB: [buf][A|B][256][64]

  const int tid  = threadIdx.x;
  const int wid  = tid >> 6;                 // 0..7
  const int lane = tid & 63;
  const int wr   = wid >> 2;                 // wave row 0..1 (128 rows each)
  const int wc   = wid & 3;                  // wave col 0..3 (64 cols each)

  const int bid  = blockIdx.x;               // 0..511
  const int swz  = ((bid & 7) << 6) | (bid >> 3);  // xcd*64 + idx (512%8==0)
  const int brow = swz >> 4;                 // 0..31
  const int bcol = swz & 15;                 // 0..15
  const size_t M0 = (size_t)brow << 8;       // *256
  const int batch = brow >> 3;               // 2048 rows/batch / 256
  const unsigned short* Ap = Xb + M0 * K_IN;
  const unsigned short* Bp = Wb + ((size_t)batch << 24) + (((size_t)bcol << 8) * K_IN);

  // staging geometry: per round l, wave covers rows [l*64+wid*8, +8)
  const int srow = lane >> 3;                // 0..7 == row&7
  const int gsl  = ((lane & 7) ^ srow) << 3; // pre-swizzled k-elem offset
  // fragment geometry
  const int lrow = lane & 15;
  const int lr7  = lane & 7;
  const int sb   = lane >> 4;                // 0..3

  f32x4 acc[8][4] = {};

#define STAGE(buf, k0)                                                         \
  {                                                                            \
    _Pragma("unroll")                                                          \
    for (int l = 0; l < 4; ++l) {                                              \
      const int rr = (l << 6) + (wid << 3);                                    \
      GLOAD_LDS(Ap + (size_t)(rr + srow) * K_IN + (size_t)((k0) + gsl),        \
                &lds[((buf) << 15) + (rr << 6)]);                              \
    }                                                                          \
    _Pragma("unroll")                                                          \
    for (int l = 0; l < 4; ++l) {                                              \
      const int rr = (l << 6) + (wid << 3);                                    \
      GLOAD_LDS(Bp + (size_t)(rr + srow) * K_IN + (size_t)((k0) + gsl),        \
                &lds[((buf) << 15) + 16384 + (rr << 6)]);                      \
    }                                                                          \
  }

#define COMPUTE(buf)                                                           \
  {                                                                            \
    const unsigned short* la = &lds[(buf) << 15];                              \
    const unsigned short* lb = &lds[((buf) << 15) + 16384];                    \
    _Pragma("unroll")                                                          \
    for (int t = 0; t < 2; ++t) {                                              \
      const int cs = (((t << 2) + sb) ^ lr7) << 3;                             \
      bf16x8 af[8], bff[4];                                                    \
      _Pragma("unroll")                                                        \
      for (int m = 0; m < 8; ++m)                                              \
        af[m] = *(const bf16x8*)&la[(((wr << 7) + (m << 4) + lrow) << 6) + cs];\
      _Pragma("unroll")                                                        \
      for (int n = 0; n < 4; ++n)                                              \
        bff[n] = *(const bf16x8*)&lb[(((wc << 6) + (n << 4) + lrow) << 6) + cs];\
      __builtin_amdgcn_s_setprio(1);                                           \
      _Pragma("unroll")                                                        \
      for (int m = 0; m < 8; ++m)                                              \
        _Pragma("unroll")                                                      \
        for (int n = 0; n < 4; ++n)                                            \
          acc[m][n] = __builtin_amdgcn_mfma_f32_16x16x32_bf16(                 \
              af[m], bff[n], acc[m][n], 0, 0, 0);                              \
      __builtin_amdgcn_s_setprio(0);                                           \
    }                                                                          \
  }

  STAGE(0, 0);                               // prologue: tile 0 -> buf0
  int cur = 0;
  for (int t = 0; t < 63; ++t) {
    STAGE(cur ^ 1, (t + 1) << 6);            // issue next tile, keep in flight
    asm volatile("s_waitcnt vmcnt(8)\n\ts_barrier" ::: "memory"); // tile t landed
    COMPUTE(cur);
    asm volatile("s_barrier" ::: "memory");  // reads done -> next STAGE safe
    cur ^= 1;
  }
  asm volatile("s_waitcnt vmcnt(0)\n\ts_barrier" ::: "memory");
  COMPUTE(cur);

  // epilogue: C/D layout col = lane&15, row = (lane>>4)*4 + j  [m89/m91]
  const int ch = lane >> 4;
  float* op = out + (M0 + (size_t)(wr << 7)) * F_OUT + ((size_t)bcol << 8) + (wc << 6);
  #pragma unroll
  for (int m = 0; m < 8; ++m)
    #pragma unroll
    for (int n = 0; n < 4; ++n)
      #pragma unroll
      for (int j = 0; j < 4; ++j)
        op[(size_t)((m << 4) + (ch << 2) + j) * F_OUT + (n << 4) + lrow] = acc[m][n][j];
#undef STAGE
#undef COMPUTE
}

// ---------------- fallback (small ws): naive, reads bf16 pairs -------------
__global__ __launch_bounds__(256) void naive_kernel(
    const float* __restrict__ x, const unsigned short* __restrict__ Wcb,
    const float* __restrict__ phase, float* __restrict__ out) {
  int n = blockIdx.x >> 4;
  int r = ((blockIdx.x & 15) << 8) | threadIdx.x;
  float cb = cosf(phase[n >> 11]);
  const float* xp = x + ((size_t)n << 12);
  const unsigned short* wc = Wcb + (((size_t)r << 12) << 1);
  float ar = 0.f, ai = 0.f;
  for (int k = 0; k < K_IN; ++k) {
    float xv = xp[k];
    ar += xv * bf2f(wc[2 * k]);
    ai += xv * bf2f(wc[2 * k + 1]);
  }
  out[((size_t)n << 12) + r] = ar + cb * ai;
}

// ---------------------------------------------------------------------------
extern "C" void kernel_launch(void* const* d_in, const int* in_sizes, int n_in,
                              void* d_out, int out_size, void* d_ws, size_t ws_size,
                              hipStream_t stream) {
  const float* x     = (const float*)d_in[0];
  const int*   rows  = (const int*)d_in[1];
  const int*   cols  = (const int*)d_in[2];
  const float* wre   = (const float*)d_in[3];
  const float* wim   = (const float*)d_in[4];
  const float* phase = (const float*)d_in[5];
  float* out = (float*)d_out;

  unsigned short* Wcb = (unsigned short*)d_ws;   // [0, 64MB) bf16 (r,i) pairs

  hipMemsetAsync(d_ws, 0, (size_t)WELEM * 4, stream);   // 64MB
  scatter_kernel<<<NNZ / 256, 256, 0, stream>>>(rows, cols, wre, wim, Wcb);

  const size_t WS_MAIN = (size_t)201326592;  // 192MB
  if (ws_size >= WS_MAIN) {
    unsigned short* Wb = (unsigned short*)((char*)d_ws + (size_t)67108864); // [64,192MB) bf16 x4
    unsigned short* Xb = (unsigned short*)d_ws;  // reuses Wcb region after fold (stream-ordered)
    fold_kernel<<<WELEM / 8 / 256, 256, 0, stream>>>(Wcb, phase, Wb);
    xconv_kernel<<<(size_t)NROW * K_IN / 8 / 256, 256, 0, stream>>>(x, Xb);
    gemm_kernel<<<512, 512, 0, stream>>>(Xb, Wb, out);
  } else {
    naive_kernel<<<NROW * 16, 256, 0, stream>>>(x, Wcb, phase, out);
  }
}